// Round 7
// baseline (5785.748 us; speedup 1.0000x reference)
//
#include <hip/hip_runtime.h>
#include <cstddef>

#define T_STEPS 1024
#define NB      64
#define DIN     128
#define HID     256

typedef unsigned short u16;
typedef unsigned int   u32;
typedef unsigned long long u64;
typedef __attribute__((ext_vector_type(8))) short short8;
typedef __attribute__((ext_vector_type(4))) float f32x4;

// ws byte offsets
#define WV_OFF   0u          // bf16 weights [2][64 nt][12 ks][64 lane][8] = 1,572,864 B
#define BIAS_OFF 1572864u    // f32 [2][1024] (row n = j*4+q interleave)
#define XB_OFF   1581056u    // bf16 x [1024][64][128] = 16,777,216 B
#define HB_OFF   18358272u   // u64 hbuf [2 par][16 grp][8 b][256 j] = 524,288 B

#define OUT_MAIN (T_STEPS * NB * 2 * HID)
#define TAIL_H   OUT_MAIN
#define TAIL_C   (OUT_MAIN + 2 * NB * HID)

__device__ __forceinline__ u16 f2bf(float f) {
  unsigned u = __float_as_uint(f);
  return (u16)((u + 0x7fffu + ((u >> 16) & 1u)) >> 16);  // RNE
}
__device__ __forceinline__ float bf2f(u16 h) {
  return __uint_as_float(((unsigned)h) << 16);
}
__device__ __forceinline__ float sigm(float v) { return 1.f / (1.f + __expf(-v)); }
__device__ __forceinline__ float tanh_fast(float x) {
  float e = __expf(-2.f * fabsf(x));
  float r = (1.f - e) / (1.f + e);
  return x < 0.f ? -r : r;
}

__global__ void prep_kernel(const float* __restrict__ x,
                            const float* __restrict__ Wih_f, const float* __restrict__ Whh_f,
                            const float* __restrict__ bih_f, const float* __restrict__ bhh_f,
                            const float* __restrict__ Wih_r, const float* __restrict__ Whh_r,
                            const float* __restrict__ bih_r, const float* __restrict__ bhh_r,
                            const float* __restrict__ hx,
                            u16* __restrict__ Wv, float* __restrict__ bias4,
                            u16* __restrict__ xb, u64* __restrict__ hbuf) {
  const int total = 786432 + 2048 + 8388608 + 32768;
  for (int i = blockIdx.x * blockDim.x + threadIdx.x; i < total;
       i += gridDim.x * blockDim.x) {
    if (i < 786432) {
      // vectorized MFMA-B layout [d][nt][ks][lane][8] (verified in r5)
      int d  = i / 393216;
      int r  = i - d * 393216;
      int nt = r / 6144;
      int r2 = r - nt * 6144;
      int ks = r2 >> 9;
      int r3 = r2 & 511;
      int lq = r3 >> 3;
      int e  = r3 & 7;
      int n = nt * 16 + (lq & 15);
      int j = n >> 2, q = n & 3;
      int g = q * HID + j;                      // torch gate row
      int kk = (lq >> 4) * 8 + e;
      int k = (ks < 4) ? (ks * 32 + kk) : (DIN + (ks - 4) * 32 + kk);
      const float* Wih = d ? Wih_r : Wih_f;
      const float* Whh = d ? Whh_r : Whh_f;
      float v = (k < DIN) ? Wih[g * DIN + k] : Whh[g * HID + (k - DIN)];
      Wv[i] = f2bf(v);
    } else if (i < 786432 + 2048) {
      int r = i - 786432;
      int d = r >> 10, n = r & 1023;
      int j = n >> 2, q = n & 3;
      int g = q * HID + j;
      bias4[r] = d ? (bih_r[g] + bhh_r[g]) : (bih_f[g] + bhh_f[g]);
    } else if (i < 786432 + 2048 + 8388608) {
      int r = i - (786432 + 2048);
      xb[r] = f2bf(x[r]);                       // [t][b][k]
    } else {
      int r = i - (786432 + 2048 + 8388608);    // (d*64+b)*256 + j
      int d = r >> 14, b = (r >> 8) & 63, j = r & 255;
      float v = hx[r];
      u16 hh = f2bf(v), hl = f2bf(v - bf2f(hh));
      int grp = d * 8 + (b >> 3), bb = b & 7;
      size_t cell = ((size_t)grp * 8 + bb) * 256 + j;
      hbuf[(size_t)16 * 8 * 256 + cell] =       // parity 1: initial h, tag 1
          ((u64)1u << 32) | ((u32)hh << 16) | hl;
      hbuf[cell] = 0ull;                        // parity 0: cleared (tag 0)
    }
  }
}

#define MFMA __builtin_amdgcn_mfma_f32_16x16x32_bf16
#define CHK(V, E) if ((u32)((V) >> 32) != want) { \
    V = __hip_atomic_load(cbp + (E), __ATOMIC_RELAXED, __HIP_MEMORY_SCOPE_AGENT); \
    bad = true; }

// 256 WGs x 256 thr. XCD-swizzled: grp = (bid&7) + 8*(bid>>7), jsl = (bid>>3)&15
// -> all 16 WGs of a group on one XCD (if XCD = bid%8), both dirs of a btile too.
// Per WG: 64 gate rows (j in [jsl*16,jsl*16+16) x4 gates), 8 batches.
// Weights live in VGPRs (48/wave). h exchange: tagged u64 cells, 1 LLC RT.
__global__ __launch_bounds__(256, 1) void lstm_tag(
    const u16* __restrict__ Wv, const float* __restrict__ bias4,
    const u16* __restrict__ xb, const float* __restrict__ cx,
    u64* __restrict__ hbuf, float* __restrict__ out) {
  __shared__ __align__(16) u16 xsh[2][16][136];   // x double-buffer, rows 8-15 zero
  __shared__ __align__(16) u16 hsh[16][520];      // h: hi [0,256) lo [256,512), rows 8-15 zero
  __shared__ __align__(16) float gl[8][68];       // [batch m][gate row nloc]

  const int tid = threadIdx.x;
  const int bid = blockIdx.x;
  const int grp = (bid & 7) + 8 * (bid >> 7);
  const int jsl = (bid >> 3) & 15;
  const int d = grp >> 3, b0 = (grp & 7) * 8;
  const int w = tid >> 6, l = tid & 63;

  // persistent weight fragments -> registers (coalesced uint4 loads)
  uint4 B[12];
  {
    const uint4* Wq4 = (const uint4*)Wv;
    const size_t base = ((size_t)(d * 64 + jsl * 4 + w) * 12) * 64 + l;
#pragma unroll
    for (int ks = 0; ks < 12; ++ks) B[ks] = Wq4[base + (size_t)ks * 64];
  }
  const float bv = bias4[d * 1024 + jsl * 64 + w * 16 + (l & 15)];

  // zero A rows 8..15
  for (int i = tid; i < 2 * 8 * 136; i += 256) {
    int pz = i / (8 * 136), rz2 = (i / 136) % 8, cz = i % 136;
    xsh[pz][8 + rz2][cz] = 0;
  }
  for (int i = tid; i < 8 * 520; i += 256) hsh[8 + i / 520][i % 520] = 0;

  // elementwise identity (tid<128): jl = gate j-slot, bb = batch
  const int jl = tid >> 3, bb = tid & 7;
  const int jglob = jsl * 16 + jl;
  float c_reg = 0.f;
  if (tid < 128) c_reg = cx[((size_t)d * NB + b0 + bb) * HID + jglob];

  const int pb = tid >> 5;              // x-park row / consumer batch
  const int pc = (tid & 31) * 4;        // x-park col
  const int cj0 = (tid & 31) * 8;       // consumer j0 (8 cells)

  // prologue: park x(t0), prefetch x(t1)
  {
    int t0 = d ? 1023 : 0;
    *(u64*)&xsh[0][pb][pc] =
        *(const u64*)&xb[((size_t)t0 * NB + b0 + pb) * DIN + pc];
  }
  u64 xv;
  {
    int t1 = d ? 1022 : 1;
    xv = *(const u64*)&xb[((size_t)t1 * NB + b0 + pb) * DIN + pc];
  }
  __syncthreads();

  for (int s = 0; s < T_STEPS; ++s) {
    const int t = d ? (1023 - s) : s;
    const int p = s & 1;
    const u32 want = (u32)(s + 1);

    // park x(t+1) into the other buffer (no reader this step)
    if (s < 1023) *(u64*)&xsh[p ^ 1][pb][pc] = xv;

    // first poll round: issue all 8 cell loads
    const u64* cbp = hbuf + (((size_t)((p ^ 1) * 16 + grp) * 8 + pb) * 256 + cj0);
    u64 v0 = __hip_atomic_load(cbp + 0, __ATOMIC_RELAXED, __HIP_MEMORY_SCOPE_AGENT);
    u64 v1 = __hip_atomic_load(cbp + 1, __ATOMIC_RELAXED, __HIP_MEMORY_SCOPE_AGENT);
    u64 v2 = __hip_atomic_load(cbp + 2, __ATOMIC_RELAXED, __HIP_MEMORY_SCOPE_AGENT);
    u64 v3 = __hip_atomic_load(cbp + 3, __ATOMIC_RELAXED, __HIP_MEMORY_SCOPE_AGENT);
    u64 v4 = __hip_atomic_load(cbp + 4, __ATOMIC_RELAXED, __HIP_MEMORY_SCOPE_AGENT);
    u64 v5 = __hip_atomic_load(cbp + 5, __ATOMIC_RELAXED, __HIP_MEMORY_SCOPE_AGENT);
    u64 v6 = __hip_atomic_load(cbp + 6, __ATOMIC_RELAXED, __HIP_MEMORY_SCOPE_AGENT);
    u64 v7 = __hip_atomic_load(cbp + 7, __ATOMIC_RELAXED, __HIP_MEMORY_SCOPE_AGENT);

    // x-part MFMA (independent of h) overlaps the poll round trip
    f32x4 acc = {bv, bv, bv, bv}, acl = {0.f, 0.f, 0.f, 0.f};
    {
      const u16* xr = &xsh[p][l & 15][(l >> 4) * 8];
      short8 Ax0 = *(const short8*)(xr);
      short8 Ax1 = *(const short8*)(xr + 32);
      short8 Ax2 = *(const short8*)(xr + 64);
      short8 Ax3 = *(const short8*)(xr + 96);
      acc = MFMA(Ax0, *(const short8*)&B[0], acc, 0, 0, 0);
      acc = MFMA(Ax1, *(const short8*)&B[1], acc, 0, 0, 0);
      acc = MFMA(Ax2, *(const short8*)&B[2], acc, 0, 0, 0);
      acc = MFMA(Ax3, *(const short8*)&B[3], acc, 0, 0, 0);
    }
    // global prefetch of x for step s+2
    if (s < 1022) {
      int tn = d ? (1021 - s) : (s + 2);
      xv = *(const u64*)&xb[((size_t)tn * NB + b0 + pb) * DIN + pc];
    }

    // finish polls (retry only stale cells; each round = one LLC RT)
    {
      bool bad = true;
      while (bad) {
        bad = false;
        CHK(v0, 0) CHK(v1, 1) CHK(v2, 2) CHK(v3, 3)
        CHK(v4, 4) CHK(v5, 5) CHK(v6, 6) CHK(v7, 7)
      }
    }
    // extract hi/lo planes and park to LDS
    {
      short8 H, L;
      H[0] = (short)(u16)(v0 >> 16); L[0] = (short)(u16)v0;
      H[1] = (short)(u16)(v1 >> 16); L[1] = (short)(u16)v1;
      H[2] = (short)(u16)(v2 >> 16); L[2] = (short)(u16)v2;
      H[3] = (short)(u16)(v3 >> 16); L[3] = (short)(u16)v3;
      H[4] = (short)(u16)(v4 >> 16); L[4] = (short)(u16)v4;
      H[5] = (short)(u16)(v5 >> 16); L[5] = (short)(u16)v5;
      H[6] = (short)(u16)(v6 >> 16); L[6] = (short)(u16)v6;
      H[7] = (short)(u16)(v7 >> 16); L[7] = (short)(u16)v7;
      *(short8*)&hsh[pb][cj0] = H;
      *(short8*)&hsh[pb][256 + cj0] = L;
    }
    asm volatile("s_waitcnt lgkmcnt(0)" ::: "memory");
    __builtin_amdgcn_s_barrier();             // B1: h parked

    // h-part MFMA (hi and lo share B fragments)
    {
      const u16* hr = &hsh[l & 15][(l >> 4) * 8];
#pragma unroll
      for (int kb = 0; kb < 8; ++kb) {
        short8 Ah = *(const short8*)(hr + 32 * kb);
        short8 Al = *(const short8*)(hr + 256 + 32 * kb);
        acc = MFMA(Ah, *(const short8*)&B[4 + kb], acc, 0, 0, 0);
        acl = MFMA(Al, *(const short8*)&B[4 + kb], acl, 0, 0, 0);
      }
    }
    acc = acc + acl;
    if (l < 32) {
      int nloc = w * 16 + (l & 15);
      int m0 = (l >> 4) * 4;
      gl[m0 + 0][nloc] = acc[0]; gl[m0 + 1][nloc] = acc[1];
      gl[m0 + 2][nloc] = acc[2]; gl[m0 + 3][nloc] = acc[3];
    }
    asm volatile("s_waitcnt lgkmcnt(0)" ::: "memory");
    __builtin_amdgcn_s_barrier();             // B2: gates published

    // elementwise + tagged h publish (single u64 store, no fences)
    if (tid < 128) {
      f32x4 g4 = *(const f32x4*)&gl[bb][4 * jl];
      float ii = sigm(g4[0]), ff = sigm(g4[1]);
      float gg = tanh_fast(g4[2]), oo = sigm(g4[3]);
      float c = ff * c_reg + ii * gg;
      c_reg = c;
      float h = oo * tanh_fast(c);
      u16 hh = f2bf(h), hl = f2bf(h - bf2f(hh));
      u64 msg = ((u64)(u32)(s + 2) << 32) | ((u32)hh << 16) | hl;
      __hip_atomic_store(hbuf + (((size_t)(p * 16 + grp) * 8 + bb) * 256 + jglob),
                         msg, __ATOMIC_RELAXED, __HIP_MEMORY_SCOPE_AGENT);
      out[((size_t)t * NB + b0 + bb) * (2 * HID) + d * HID + jglob] = h;
      if (s == T_STEPS - 1) {
        out[TAIL_H + ((size_t)d * NB + b0 + bb) * HID + jglob] = h;
        out[TAIL_C + ((size_t)d * NB + b0 + bb) * HID + jglob] = c;
      }
    }
  }
}

extern "C" void kernel_launch(void* const* d_in, const int* in_sizes, int n_in,
                              void* d_out, int out_size, void* d_ws, size_t ws_size,
                              hipStream_t stream) {
  const float* x     = (const float*)d_in[0];
  const float* hx    = (const float*)d_in[1];
  const float* cx    = (const float*)d_in[2];
  const float* Wih_f = (const float*)d_in[3];
  const float* Whh_f = (const float*)d_in[4];
  const float* bih_f = (const float*)d_in[5];
  const float* bhh_f = (const float*)d_in[6];
  const float* Wih_r = (const float*)d_in[7];
  const float* Whh_r = (const float*)d_in[8];
  const float* bih_r = (const float*)d_in[9];
  const float* bhh_r = (const float*)d_in[10];
  float* out = (float*)d_out;

  u16* Wv      = (u16*)((char*)d_ws + WV_OFF);
  float* bias4 = (float*)((char*)d_ws + BIAS_OFF);
  u16* xb      = (u16*)((char*)d_ws + XB_OFF);
  u64* hbuf    = (u64*)((char*)d_ws + HB_OFF);

  hipLaunchKernelGGL(prep_kernel, dim3(2048), dim3(256), 0, stream,
                     x, Wih_f, Whh_f, bih_f, bhh_f, Wih_r, Whh_r, bih_r, bhh_r,
                     hx, Wv, bias4, xb, hbuf);
  hipLaunchKernelGGL(lstm_tag, dim3(256), dim3(256), 0, stream,
                     Wv, bias4, xb, cx, hbuf, out);
}

// Round 8
// 3395.367 us; speedup vs baseline: 1.7040x; 1.7040x over previous
//
#include <hip/hip_runtime.h>
#include <cstddef>

#define T_STEPS 1024
#define NB      64
#define DIN     128
#define HID     256

typedef unsigned short u16;
typedef unsigned int   u32;
typedef unsigned long long u64;
typedef __attribute__((ext_vector_type(8))) short short8;
typedef __attribute__((ext_vector_type(4))) float f32x4;

// ws byte offsets
#define WG_OFF   0u          // bf16 weights [2][1024 rows j*4+q][384 k] = 1,572,864 B
#define BIAS_OFF 1572864u    // f32 [2][1024]
#define XB_OFF   1581056u    // bf16 x [1024][64][128] = 16,777,216 B
#define HB_OFF   18358272u   // u32 hbuf [2 par][16 grp][8 b][256 j] = 262,144 B

#define OUT_MAIN (T_STEPS * NB * 2 * HID)
#define TAIL_H   OUT_MAIN
#define TAIL_C   (OUT_MAIN + 2 * NB * HID)

__device__ __forceinline__ u16 f2bf(float f) {
  unsigned u = __float_as_uint(f);
  return (u16)((u + 0x7fffu + ((u >> 16) & 1u)) >> 16);  // RNE
}
__device__ __forceinline__ float sigm(float v) { return 1.f / (1.f + __expf(-v)); }
__device__ __forceinline__ float tanh_fast(float x) {
  float e = __expf(-2.f * fabsf(x));
  float r = (1.f - e) / (1.f + e);
  return x < 0.f ? -r : r;
}

__global__ void prep_kernel(const float* __restrict__ x,
                            const float* __restrict__ Wih_f, const float* __restrict__ Whh_f,
                            const float* __restrict__ bih_f, const float* __restrict__ bhh_f,
                            const float* __restrict__ Wih_r, const float* __restrict__ Whh_r,
                            const float* __restrict__ bih_r, const float* __restrict__ bhh_r,
                            const float* __restrict__ hx,
                            u16* __restrict__ Wg, float* __restrict__ bias4,
                            u16* __restrict__ xb, u32* __restrict__ hbuf) {
  const int total = 786432 + 2048 + 8388608 + 32768;
  for (int i = blockIdx.x * blockDim.x + threadIdx.x; i < total;
       i += gridDim.x * blockDim.x) {
    if (i < 786432) {
      int d = i / 393216;
      int r = i - d * 393216;
      int rowg = r / 384, k = r - rowg * 384;   // rowg = j*4+q interleaved
      int j = rowg >> 2, q = rowg & 3;
      int g = q * HID + j;                      // torch gate row
      const float* Wih = d ? Wih_r : Wih_f;
      const float* Whh = d ? Whh_r : Whh_f;
      float v = (k < DIN) ? Wih[g * DIN + k] : Whh[g * HID + (k - DIN)];
      Wg[i] = f2bf(v);
    } else if (i < 786432 + 2048) {
      int r = i - 786432;
      int d = r >> 10, rowg = r & 1023;
      int j = rowg >> 2, q = rowg & 3;
      int g = q * HID + j;
      bias4[r] = d ? (bih_r[g] + bhh_r[g]) : (bih_f[g] + bhh_f[g]);
    } else if (i < 786432 + 2048 + 8388608) {
      int r = i - (786432 + 2048);
      xb[r] = f2bf(x[r]);                       // [t][b][k]
    } else {
      int r = i - (786432 + 2048 + 8388608);    // (d*64+b)*256 + j
      int d = r >> 14, b = (r >> 8) & 63, j = r & 255;
      int grp = d * 8 + (b >> 3), bb = b & 7;
      size_t cell = ((size_t)grp * 8 + bb) * 256 + j;
      hbuf[16 * 8 * 256 + cell] = ((u32)1u << 16) | f2bf(hx[r]);  // parity 1: tag 1
      hbuf[cell] = 0u;                                            // parity 0: clear
    }
  }
}

#define MFMA __builtin_amdgcn_mfma_f32_16x16x32_bf16
#define CHK(V, E) if ((((u32)((V) >> 16) & 0xffffu) != wt) || \
                      (((u32)((V) >> 48) & 0xffffu) != wt)) { \
    V = __hip_atomic_load(cbp + (E), __ATOMIC_RELAXED, __HIP_MEMORY_SCOPE_AGENT); \
    bad = true; }

// 256 WGs x 256 thr. grp = (bid&7)+8*(bid>>7) (group co-XCD under round-robin),
// jsl = (bid>>3)&15. Per WG: 64 gate rows (j in [jsl*16,+16) x 4 gates), 8 batches.
// Weights in LDS. h exchange: tagged u32 cells (1 LLC round trip, no flags/RMW).
__global__ __launch_bounds__(256, 1) void lstm_tag2(
    const u16* __restrict__ Wg, const float* __restrict__ bias4,
    const u16* __restrict__ xb, const float* __restrict__ cx,
    u32* __restrict__ hbuf, float* __restrict__ out) {
  extern __shared__ char smem[];
  u16* wl   = (u16*)smem;                 // [64][392]   50,176 B
  u16* xsh  = (u16*)(smem + 50176);       // [2][16][136] 8,704 B (rows 8-15 zero)
  u16* hsh  = (u16*)(smem + 58880);       // [16][264]    8,448 B (rows 8-15 zero)
  float* gl = (float*)(smem + 67328);     // [8][68]      2,176 B

  const int tid = threadIdx.x;
  const int bid = blockIdx.x;
  const int grp = (bid & 7) + 8 * (bid >> 7);
  const int jsl = (bid >> 3) & 15;
  const int d = grp >> 3, b0 = (grp & 7) * 8;
  const int w = tid >> 6, l = tid & 63;

  // one-time: weight slice -> LDS (dword stride 196 == 4 mod 32, ~2-way)
  {
    const u32* src = (const u32*)(Wg + (size_t)(d * 1024 + jsl * 64) * 384);
    u32* dst = (u32*)wl;
    for (int iu = tid; iu < 64 * 192; iu += 256) {
      int r = iu / 192, c = iu - r * 192;
      dst[r * 196 + c] = src[iu];
    }
  }
  // zero A rows 8..15
  for (int i = tid; i < 2 * 8 * 136; i += 256) {
    int pz = i / (8 * 136), rz = (i / 136) & 7, cz = i % 136;
    xsh[(pz * 16 + 8 + rz) * 136 + cz] = 0;
  }
  for (int i = tid; i < 8 * 264; i += 256) hsh[(8 + i / 264) * 264 + (i % 264)] = 0;

  const float bv = bias4[d * 1024 + jsl * 64 + w * 16 + (l & 15)];

  // elementwise identity (tid<128): ebb = batch, ejj = j slot
  const int ebb = tid >> 4, ejj = tid & 15;
  const int jglob = jsl * 16 + ejj;
  float c_reg = 0.f;
  if (tid < 128) c_reg = cx[((size_t)d * NB + b0 + ebb) * HID + jglob];

  const int pb = tid >> 5;            // x-park row / consumer batch
  const int pc = (tid & 31) * 4;      // x-park col
  const int cj0 = (tid & 31) * 8;     // consumer j0 (8 cells)

  // prologue: park x(t0), prefetch x(t1)
  { int t0 = d ? 1023 : 0;
    *(u64*)&xsh[(0 * 16 + pb) * 136 + pc] =
        *(const u64*)&xb[((size_t)t0 * NB + b0 + pb) * DIN + pc]; }
  u64 xv;
  { int t1 = d ? 1022 : 1;
    xv = *(const u64*)&xb[((size_t)t1 * NB + b0 + pb) * DIN + pc]; }
  __syncthreads();

  for (int s = 0; s < T_STEPS; ++s) {
    const int t = d ? (1023 - s) : s;
    const int p = s & 1;
    const u32 wt = (u32)(s + 1) & 0xffffu;

    // park x(t+1) into the other buffer (no reader this step)
    if (s < 1023) *(u64*)&xsh[((p ^ 1) * 16 + pb) * 136 + pc] = xv;

    // first poll round: issue all 8 cell loads (4 x u64)
    const u64* cbp = (const u64*)(hbuf + (((size_t)((p ^ 1) * 16 + grp)) * 8 + pb) * 256 + cj0);
    u64 v0 = __hip_atomic_load(cbp + 0, __ATOMIC_RELAXED, __HIP_MEMORY_SCOPE_AGENT);
    u64 v1 = __hip_atomic_load(cbp + 1, __ATOMIC_RELAXED, __HIP_MEMORY_SCOPE_AGENT);
    u64 v2 = __hip_atomic_load(cbp + 2, __ATOMIC_RELAXED, __HIP_MEMORY_SCOPE_AGENT);
    u64 v3 = __hip_atomic_load(cbp + 3, __ATOMIC_RELAXED, __HIP_MEMORY_SCOPE_AGENT);

    // x-part MFMA (independent of h) hides the poll round trip
    f32x4 acc = {bv, bv, bv, bv};
    {
      const u16* xr = &xsh[(p * 16 + (l & 15)) * 136 + (l >> 4) * 8];
      const u16* wr = wl + (size_t)(w * 16 + (l & 15)) * 392 + (l >> 4) * 8;
      acc = MFMA(*(const short8*)(xr + 0),  *(const short8*)(wr + 0),  acc, 0, 0, 0);
      acc = MFMA(*(const short8*)(xr + 32), *(const short8*)(wr + 32), acc, 0, 0, 0);
      acc = MFMA(*(const short8*)(xr + 64), *(const short8*)(wr + 64), acc, 0, 0, 0);
      acc = MFMA(*(const short8*)(xr + 96), *(const short8*)(wr + 96), acc, 0, 0, 0);
    }
    // global prefetch of x for step s+2
    if (s < 1022) {
      int tn = d ? (1021 - s) : (s + 2);
      xv = *(const u64*)&xb[((size_t)tn * NB + b0 + pb) * DIN + pc];
    }

    // finish polls (reload only stale u64s)
    {
      bool bad = true;
      while (bad) {
        bad = false;
        CHK(v0, 0) CHK(v1, 1) CHK(v2, 2) CHK(v3, 3)
      }
    }
    // park h (bf16 payload = low 16 bits of each u32 cell)
    {
      short8 H;
      H[0] = (short)(u16)v0; H[1] = (short)(u16)(v0 >> 32);
      H[2] = (short)(u16)v1; H[3] = (short)(u16)(v1 >> 32);
      H[4] = (short)(u16)v2; H[5] = (short)(u16)(v2 >> 32);
      H[6] = (short)(u16)v3; H[7] = (short)(u16)(v3 >> 32);
      *(short8*)&hsh[pb * 264 + cj0] = H;
    }
    asm volatile("s_waitcnt lgkmcnt(0)" ::: "memory");
    __builtin_amdgcn_s_barrier();             // B1: h parked

    // h-part MFMA
    {
      const u16* hr = &hsh[(l & 15) * 264 + (l >> 4) * 8];
      const u16* wr = wl + (size_t)(w * 16 + (l & 15)) * 392 + 128 + (l >> 4) * 8;
#pragma unroll
      for (int kb = 0; kb < 8; ++kb)
        acc = MFMA(*(const short8*)(hr + 32 * kb), *(const short8*)(wr + 32 * kb),
                   acc, 0, 0, 0);
    }
    if (l < 32) {
      int n = w * 16 + (l & 15);
      int m0 = (l >> 4) * 4;
      gl[(m0 + 0) * 68 + n] = acc[0]; gl[(m0 + 1) * 68 + n] = acc[1];
      gl[(m0 + 2) * 68 + n] = acc[2]; gl[(m0 + 3) * 68 + n] = acc[3];
    }
    asm volatile("s_waitcnt lgkmcnt(0)" ::: "memory");
    __builtin_amdgcn_s_barrier();             // B2: gates published

    // elementwise + tagged publish (single u32 agent store, no drains)
    if (tid < 128) {
      f32x4 g4 = *(const f32x4*)&gl[ebb * 68 + 4 * ejj];
      float ii = sigm(g4[0]), ff = sigm(g4[1]);
      float gg = tanh_fast(g4[2]), oo = sigm(g4[3]);
      float c = ff * c_reg + ii * gg;
      c_reg = c;
      float h = oo * tanh_fast(c);
      u32 msg = ((u32)((s + 2) & 0xffff) << 16) | f2bf(h);
      __hip_atomic_store(hbuf + (((size_t)(p * 16 + grp)) * 8 + ebb) * 256 + jglob,
                         msg, __ATOMIC_RELAXED, __HIP_MEMORY_SCOPE_AGENT);
      out[((size_t)t * NB + b0 + ebb) * (2 * HID) + d * HID + jglob] = h;
      if (s == T_STEPS - 1) {
        out[TAIL_H + ((size_t)d * NB + b0 + ebb) * HID + jglob] = h;
        out[TAIL_C + ((size_t)d * NB + b0 + ebb) * HID + jglob] = c;
      }
    }
  }
}

extern "C" void kernel_launch(void* const* d_in, const int* in_sizes, int n_in,
                              void* d_out, int out_size, void* d_ws, size_t ws_size,
                              hipStream_t stream) {
  const float* x     = (const float*)d_in[0];
  const float* hx    = (const float*)d_in[1];
  const float* cx    = (const float*)d_in[2];
  const float* Wih_f = (const float*)d_in[3];
  const float* Whh_f = (const float*)d_in[4];
  const float* bih_f = (const float*)d_in[5];
  const float* bhh_f = (const float*)d_in[6];
  const float* Wih_r = (const float*)d_in[7];
  const float* Whh_r = (const float*)d_in[8];
  const float* bih_r = (const float*)d_in[9];
  const float* bhh_r = (const float*)d_in[10];
  float* out = (float*)d_out;

  u16* Wg      = (u16*)((char*)d_ws + WG_OFF);
  float* bias4 = (float*)((char*)d_ws + BIAS_OFF);
  u16* xb      = (u16*)((char*)d_ws + XB_OFF);
  u32* hbuf    = (u32*)((char*)d_ws + HB_OFF);

  hipFuncSetAttribute((const void*)lstm_tag2,
                      hipFuncAttributeMaxDynamicSharedMemorySize, 69504);

  hipLaunchKernelGGL(prep_kernel, dim3(2048), dim3(256), 0, stream,
                     x, Wih_f, Whh_f, bih_f, bhh_f, Wih_r, Whh_r, bih_r, bhh_r,
                     hx, Wg, bias4, xb, hbuf);
  hipLaunchKernelGGL(lstm_tag2, dim3(256), dim3(256), 69504, stream,
                     Wg, bias4, xb, cx, hbuf, out);
}

// Round 9
// 2167.161 us; speedup vs baseline: 2.6697x; 1.5667x over previous
//
#include <hip/hip_runtime.h>
#include <cstddef>

#define T_STEPS 1024
#define NB      64
#define DIN     128
#define HID     256
#define WPG     16

typedef unsigned short u16;
typedef unsigned int   u32;
typedef unsigned long long u64;
typedef __attribute__((ext_vector_type(8))) short short8;
typedef __attribute__((ext_vector_type(4))) float f32x4;

// ws byte offsets
#define WG_OFF   0u          // bf16 weights [2][1024 rows j*4+q][384 k] = 1,572,864 B
#define BIAS_OFF 1572864u    // f32 [2][1024]
#define XB_OFF   1581056u    // bf16 x [1024][64][128] = 16,777,216 B
#define HB_OFF   18358272u   // u16 hbuf [2 par][8 grp][16 b][256 j] = 131,072 B
#define FL_OFF   18489344u   // u32 flags [8 grp][1024 steps] = 32,768 B

#define OUT_MAIN (T_STEPS * NB * 2 * HID)
#define TAIL_H   OUT_MAIN
#define TAIL_C   (OUT_MAIN + 2 * NB * HID)

__device__ __forceinline__ u16 f2bf(float f) {
  unsigned u = __float_as_uint(f);
  return (u16)((u + 0x7fffu + ((u >> 16) & 1u)) >> 16);  // RNE
}
__device__ __forceinline__ float sigm(float v) { return 1.f / (1.f + __expf(-v)); }
__device__ __forceinline__ float tanh_fast(float x) {
  float e = __expf(-2.f * fabsf(x));
  float r = (1.f - e) / (1.f + e);
  return x < 0.f ? -r : r;
}

__global__ void prep_kernel(const float* __restrict__ x,
                            const float* __restrict__ Wih_f, const float* __restrict__ Whh_f,
                            const float* __restrict__ bih_f, const float* __restrict__ bhh_f,
                            const float* __restrict__ Wih_r, const float* __restrict__ Whh_r,
                            const float* __restrict__ bih_r, const float* __restrict__ bhh_r,
                            const float* __restrict__ hx,
                            u16* __restrict__ Wg, float* __restrict__ bias4,
                            u16* __restrict__ xb, u16* __restrict__ hbuf,
                            u32* __restrict__ flags) {
  // segments: W 786432 | bias 2048 | xb 8388608 | hx-cells 32768 | flags 8192
  const int total = 786432 + 2048 + 8388608 + 32768 + 8192;
  for (int i = blockIdx.x * blockDim.x + threadIdx.x; i < total;
       i += gridDim.x * blockDim.x) {
    if (i < 786432) {
      int d = i / 393216;
      int r = i - d * 393216;
      int rowg = r / 384, k = r - rowg * 384;   // rowg = j*4+q interleaved
      int j = rowg >> 2, q = rowg & 3;
      int g = q * HID + j;                      // torch gate row
      const float* Wih = d ? Wih_r : Wih_f;
      const float* Whh = d ? Whh_r : Whh_f;
      float v = (k < DIN) ? Wih[g * DIN + k] : Whh[g * HID + (k - DIN)];
      Wg[i] = f2bf(v);
    } else if (i < 786432 + 2048) {
      int r = i - 786432;
      int d = r >> 10, rowg = r & 1023;
      int j = rowg >> 2, q = rowg & 3;
      int g = q * HID + j;
      bias4[r] = d ? (bih_r[g] + bhh_r[g]) : (bih_f[g] + bhh_f[g]);
    } else if (i < 786432 + 2048 + 8388608) {
      int r = i - (786432 + 2048);
      xb[r] = f2bf(x[r]);                       // [t][b][k]
    } else if (i < 786432 + 2048 + 8388608 + 32768) {
      int r = i - (786432 + 2048 + 8388608);    // (d*64+b)*256 + j
      int d = r >> 14, b = (r >> 8) & 63, j = r & 255;
      int grp = d * 4 + (b >> 4), bb = b & 15;
      hbuf[((size_t)(8 + grp) * 16 + bb) * 256 + j] = f2bf(hx[r]);  // parity 1
      hbuf[((size_t)(0 + grp) * 16 + bb) * 256 + j] = 0;            // parity 0
    } else {
      int r = i - (786432 + 2048 + 8388608 + 32768);  // g*1024 + s
      flags[r] = ((r & 1023) == 0) ? (u32)WPG : 0u;   // step 0 pre-released
    }
  }
}

#define MFMA __builtin_amdgcn_mfma_f32_16x16x32_bf16
#define ALD64(P) __hip_atomic_load((P), __ATOMIC_RELAXED, __HIP_MEMORY_SCOPE_AGENT)

// 128 WGs x 256 thr. grp = bid&7 (co-XCD under round-robin), jsl = bid>>3.
// grp = d*4 + btile: 8 groups x 16 WGs. Per WG: 64 gate rows, 16 batches
// (full MFMA A-tile). Weights in LDS. Exchange: r4-style flag protocol --
// vmcnt-drained h stores -> fetch_add -> tid0 spin -> loads hidden under x-GEMM.
__global__ __launch_bounds__(256, 1) void lstm_flag(
    const u16* __restrict__ Wg, const float* __restrict__ bias4,
    const u16* __restrict__ xb, const float* __restrict__ cx,
    u16* __restrict__ hbuf, u32* __restrict__ flags,
    float* __restrict__ out) {
  extern __shared__ char smem[];
  u16* wl   = (u16*)smem;                 // [64][392]    50,176 B
  u16* xsh  = (u16*)(smem + 50176);       // [2][16][136]  8,704 B
  u16* hsh  = (u16*)(smem + 58880);       // [16][264]     8,448 B
  float* gl = (float*)(smem + 67328);     // [16][68]      4,352 B  (tot 71,680)

  const int tid = threadIdx.x;
  const int bid = blockIdx.x;
  const int grp = bid & 7;
  const int jsl = bid >> 3;
  const int d = grp >> 2, b0 = (grp & 3) * 16;
  const int w = tid >> 6, l = tid & 63;

  // one-time: weight slice -> LDS (dword stride 196, quad-uniform banking)
  {
    const u32* src = (const u32*)(Wg + (size_t)(d * 1024 + jsl * 64) * 384);
    u32* dst = (u32*)wl;
    for (int iu = tid; iu < 64 * 192; iu += 256) {
      int r = iu / 192, c = iu - r * 192;
      dst[r * 196 + c] = src[iu];
    }
  }
  const float bv = bias4[d * 1024 + jsl * 64 + w * 16 + (l & 15)];

  // elementwise identity: 1 cell/thread: eb = batch, ej = local j
  const int eb = tid >> 4, ej = tid & 15;
  const int jglob = jsl * 16 + ej;
  float c_reg = cx[((size_t)d * NB + b0 + eb) * HID + jglob];

  const int xr_row = tid >> 4;            // x stage row (16 batches)
  const int xc = (tid & 15) * 8;          // 8 u16 = 16 B per thread
  const int pb = tid >> 4;                // h consumer batch
  const int cj0 = (tid & 15) * 16;        // 16 h cells per thread

  // prologue: stage x(t0), prefetch x(t1), issue h(init) loads (parity 1)
  { int t0 = d ? 1023 : 0;
    *(uint4*)&xsh[(0 * 16 + xr_row) * 136 + xc] =
        *(const uint4*)&xb[((size_t)t0 * NB + b0 + xr_row) * DIN + xc]; }
  uint4 xv;
  { int t1 = d ? 1022 : 1;
    xv = *(const uint4*)&xb[((size_t)t1 * NB + b0 + xr_row) * DIN + xc]; }
  u64 h0, h1, h2, h3;
  { const u64* hp = (const u64*)(hbuf + ((size_t)(8 + grp) * 16 + pb) * 256 + cj0);
    h0 = ALD64(hp + 0); h1 = ALD64(hp + 1); h2 = ALD64(hp + 2); h3 = ALD64(hp + 3); }
  __syncthreads();

  for (int s = 0; s < T_STEPS; ++s) {
    const int p = s & 1;
    const int t = d ? (1023 - s) : s;

    // park x(s+1) into the other buffer
    if (s < 1023) *(uint4*)&xsh[((p ^ 1) * 16 + xr_row) * 136 + xc] = xv;

    // x-part MFMA (hides in-flight h loads)
    f32x4 acc = {bv, bv, bv, bv};
    {
      const u16* xr = &xsh[(p * 16 + (l & 15)) * 136 + (l >> 4) * 8];
      const u16* wr = wl + (size_t)(w * 16 + (l & 15)) * 392 + (l >> 4) * 8;
      acc = MFMA(*(const short8*)(xr + 0),  *(const short8*)(wr + 0),  acc, 0, 0, 0);
      acc = MFMA(*(const short8*)(xr + 32), *(const short8*)(wr + 32), acc, 0, 0, 0);
      acc = MFMA(*(const short8*)(xr + 64), *(const short8*)(wr + 64), acc, 0, 0, 0);
      acc = MFMA(*(const short8*)(xr + 96), *(const short8*)(wr + 96), acc, 0, 0, 0);
    }
    // park h (waits vmcnt on h regs only)
    {
      uint4 H0, H1;
      H0.x = (u32)h0; H0.y = (u32)(h0 >> 32); H0.z = (u32)h1; H0.w = (u32)(h1 >> 32);
      H1.x = (u32)h2; H1.y = (u32)(h2 >> 32); H1.z = (u32)h3; H1.w = (u32)(h3 >> 32);
      *(uint4*)&hsh[pb * 264 + cj0] = H0;
      *(uint4*)&hsh[pb * 264 + cj0 + 8] = H1;
    }
    asm volatile("s_waitcnt lgkmcnt(0)" ::: "memory");
    __builtin_amdgcn_s_barrier();                // B1: h parked

    // h-part MFMA
    {
      const u16* hr = &hsh[(l & 15) * 264 + (l >> 4) * 8];
      const u16* wr = wl + (size_t)(w * 16 + (l & 15)) * 392 + 128 + (l >> 4) * 8;
#pragma unroll
      for (int kb = 0; kb < 8; ++kb)
        acc = MFMA(*(const short8*)(hr + 32 * kb), *(const short8*)(wr + 32 * kb),
                   acc, 0, 0, 0);
    }
    {
      int n = w * 16 + (l & 15);
      int m0 = (l >> 4) * 4;
      gl[(m0 + 0) * 68 + n] = acc[0]; gl[(m0 + 1) * 68 + n] = acc[1];
      gl[(m0 + 2) * 68 + n] = acc[2]; gl[(m0 + 3) * 68 + n] = acc[3];
    }
    asm volatile("s_waitcnt lgkmcnt(0)" ::: "memory");
    __builtin_amdgcn_s_barrier();                // B2: gates published

    // elementwise (all 256 threads) + agent h-store
    f32x4 g4 = *(const f32x4*)&gl[eb * 68 + 4 * ej];
    float ii = sigm(g4[0]), ff = sigm(g4[1]);
    float gg = tanh_fast(g4[2]), oo = sigm(g4[3]);
    float c = ff * c_reg + ii * gg;
    c_reg = c;
    float h = oo * tanh_fast(c);
    u16 hb16 = f2bf(h);
    __hip_atomic_store(hbuf + ((size_t)(p * 8 + grp) * 16 + eb) * 256 + jglob,
                       hb16, __ATOMIC_RELAXED, __HIP_MEMORY_SCOPE_AGENT);
    asm volatile("s_waitcnt vmcnt(0)" ::: "memory");   // h at LLC
    __builtin_amdgcn_s_barrier();                // B3: all h stores drained
    if (tid == 0 && s < 1023)
      __hip_atomic_fetch_add(flags + grp * 1024 + (s + 1), 1u,
                             __ATOMIC_RELAXED, __HIP_MEMORY_SCOPE_AGENT);
    // fire-and-forget stores after the flag
    out[((size_t)t * NB + b0 + eb) * (2 * HID) + d * HID + jglob] = h;
    if (s == 1023) {
      out[TAIL_H + ((size_t)d * NB + b0 + eb) * HID + jglob] = h;
      out[TAIL_C + ((size_t)d * NB + b0 + eb) * HID + jglob] = c;
    }
    // x prefetch for s+2
    if (s < 1022) {
      int tn = d ? (1021 - s) : (s + 2);
      xv = *(const uint4*)&xb[((size_t)tn * NB + b0 + xr_row) * DIN + xc];
    }
    if (s < 1023) {
      if (tid == 0) {
        const u32* fp = flags + grp * 1024 + (s + 1);
        while (__hip_atomic_load(fp, __ATOMIC_RELAXED, __HIP_MEMORY_SCOPE_AGENT) < WPG)
          __builtin_amdgcn_s_sleep(1);
      }
      __builtin_amdgcn_s_barrier();              // B4: group released
      // issue h(s) loads (parity p) -- hidden under next step's x-GEMM
      const u64* hp = (const u64*)(hbuf + ((size_t)(p * 8 + grp) * 16 + pb) * 256 + cj0);
      h0 = ALD64(hp + 0); h1 = ALD64(hp + 1); h2 = ALD64(hp + 2); h3 = ALD64(hp + 3);
    }
  }
}

extern "C" void kernel_launch(void* const* d_in, const int* in_sizes, int n_in,
                              void* d_out, int out_size, void* d_ws, size_t ws_size,
                              hipStream_t stream) {
  const float* x     = (const float*)d_in[0];
  const float* hx    = (const float*)d_in[1];
  const float* cx    = (const float*)d_in[2];
  const float* Wih_f = (const float*)d_in[3];
  const float* Whh_f = (const float*)d_in[4];
  const float* bih_f = (const float*)d_in[5];
  const float* bhh_f = (const float*)d_in[6];
  const float* Wih_r = (const float*)d_in[7];
  const float* Whh_r = (const float*)d_in[8];
  const float* bih_r = (const float*)d_in[9];
  const float* bhh_r = (const float*)d_in[10];
  float* out = (float*)d_out;

  u16* Wg      = (u16*)((char*)d_ws + WG_OFF);
  float* bias4 = (float*)((char*)d_ws + BIAS_OFF);
  u16* xb      = (u16*)((char*)d_ws + XB_OFF);
  u16* hbuf    = (u16*)((char*)d_ws + HB_OFF);
  u32* flags   = (u32*)((char*)d_ws + FL_OFF);

  // 86,016 B dynamic LDS: > 81,920 so two WGs can never share a CU.
  hipFuncSetAttribute((const void*)lstm_flag,
                      hipFuncAttributeMaxDynamicSharedMemorySize, 86016);

  hipLaunchKernelGGL(prep_kernel, dim3(2048), dim3(256), 0, stream,
                     x, Wih_f, Whh_f, bih_f, bhh_f, Wih_r, Whh_r, bih_r, bhh_r,
                     hx, Wg, bias4, xb, hbuf, flags);
  hipLaunchKernelGGL(lstm_flag, dim3(128), dim3(256), 86016, stream,
                     Wg, bias4, xb, cx, hbuf, flags, out);
}